// Round 1
// 680.334 us; speedup vs baseline: 1.0442x; 1.0442x over previous
//
#include <hip/hip_runtime.h>

typedef short short8 __attribute__((ext_vector_type(8)));
typedef float floatx4 __attribute__((ext_vector_type(4)));
typedef unsigned short u16;

// fp32 -> bf16 round-to-nearest-even (bit math)
__device__ __forceinline__ u16 cvt_bf(float x) {
  unsigned u = __float_as_uint(x);
  unsigned r = 0x7FFFu + ((u >> 16) & 1u);
  return (u16)((u + r) >> 16);
}
__device__ __forceinline__ float bf2f(u16 h) {
  return __uint_as_float(((unsigned)h) << 16);
}
// async global->LDS, 16B/lane; LDS dest = uniform base + lane*16
__device__ __forceinline__ void gll16(const u16* g, u16* l) {
  __builtin_amdgcn_global_load_lds(
      (__attribute__((address_space(1))) void*)(void*)const_cast<u16*>(g),
      (__attribute__((address_space(3))) void*)(void*)l, 16, 0, 0);
}
// fast tanh/sigmoid via v_exp (args bounded ~|6| here; |x| form is overflow-safe)
__device__ __forceinline__ float fast_tanh(float x) {
  float t = __expf(-2.f * fabsf(x));
  float r = 1.f - 2.f * t / (1.f + t);
  return copysignf(r, x);
}
__device__ __forceinline__ float fast_sigm(float x) {
  return 1.f / (1.f + __expf(-x));
}

// ---------------------------------------------------------------------------
// Segmented fp32 -> bf16 convert, 2048 elems/block. src==nullptr => write zeros.
#define MAXSEG 13
struct ConvArgs {
  const float* src[MAXSEG];
  u16* dst[MAXSEG];
  unsigned lw[MAXSEG];       // row = e >> lw, col = e & ((1<<lw)-1)
  unsigned dstride[MAXSEG];
  unsigned blk0[MAXSEG + 1];
  int nseg;
};
__global__ __launch_bounds__(256)
void convert_seg(ConvArgs a) {
  const unsigned blk = blockIdx.x;
  int s = 0;
  for (int i = 1; i < a.nseg; ++i) if (blk >= a.blk0[i]) s = i;
  const unsigned e0 = (blk - a.blk0[s]) * 2048u + threadIdx.x * 8u;
  short8 p = {};
  u16* d;
  const float* src = a.src[s];
  if (src) {
    const float4 v0 = *(const float4*)(src + e0);
    const float4 v1 = *(const float4*)(src + e0 + 4);
    const unsigned row = e0 >> a.lw[s];
    const unsigned col = e0 & ((1u << a.lw[s]) - 1u);
    d = a.dst[s] + (size_t)row * a.dstride[s] + col;
    p[0] = (short)cvt_bf(v0.x); p[1] = (short)cvt_bf(v0.y);
    p[2] = (short)cvt_bf(v0.z); p[3] = (short)cvt_bf(v0.w);
    p[4] = (short)cvt_bf(v1.x); p[5] = (short)cvt_bf(v1.y);
    p[6] = (short)cvt_bf(v1.z); p[7] = (short)cvt_bf(v1.w);
  } else {
    d = a.dst[s] + e0;       // linear zero-fill (scores)
  }
  *(short8*)d = p;
}
// flat fp32 -> bf16 (fallback clip chunks)
__global__ __launch_bounds__(256)
void conv_flat(const float* __restrict__ src, u16* __restrict__ dst) {
  const size_t e = (size_t)blockIdx.x * 2048 + threadIdx.x * 8;
  const float4 v0 = *(const float4*)(src + e);
  const float4 v1 = *(const float4*)(src + e + 4);
  short8 p;
  p[0] = (short)cvt_bf(v0.x); p[1] = (short)cvt_bf(v0.y);
  p[2] = (short)cvt_bf(v0.z); p[3] = (short)cvt_bf(v0.w);
  p[4] = (short)cvt_bf(v1.x); p[5] = (short)cvt_bf(v1.y);
  p[6] = (short)cvt_bf(v1.z); p[7] = (short)cvt_bf(v1.w);
  *(short8*)(dst + e) = p;
}
__global__ __launch_bounds__(256)
void zerof(float* __restrict__ p) { p[blockIdx.x * 256 + threadIdx.x] = 0.f; }

// ---------------------------------------------------------------------------
// m97-style bf16 GEMM tile body: 128x128 tile, BK=64, 256 thr / 4 waves.
// A[M,K] stride sa, B[N,K]^T stride sb. Staging: global_load_lds 16B,
// rows 128 B, 8-slot XOR swizzle (<=2-way = free).
__device__ __forceinline__ void gemm_body(
    const u16* __restrict__ A, int sa, const u16* __restrict__ B, int sb,
    int K, int Mbase, int Nbase, u16* sA, u16* sB, floatx4 (&acc)[4][4])
{
  const int tid = threadIdx.x, lane = tid & 63, w = tid >> 6;
  const int quad = lane >> 4, l15 = lane & 15;
  const int wm = w >> 1, wn = w & 1;
  const int srow = lane >> 3;                // 0..7 within 8-row chunk
  const int sslot = (lane & 7) ^ srow;       // fetch-side xor swizzle

  for (int k0 = 0; k0 < K; k0 += 64) {
    __syncthreads();   // prev tile consumed
#pragma unroll
    for (int j = 0; j < 4; ++j) {
      const int c = w + 4 * j;               // chunk 0..15 (8 rows x 128 B)
      const int row = c * 8 + srow;
      gll16(A + (size_t)(Mbase + row) * sa + k0 + sslot * 8, &sA[c * 512]);
      gll16(B + (size_t)(Nbase + row) * sb + k0 + sslot * 8, &sB[c * 512]);
    }
    __syncthreads();   // barrier drains vmcnt
#pragma unroll
    for (int ks = 0; ks < 2; ++ks) {
      short8 af[4], bf[4];
#pragma unroll
      for (int mt = 0; mt < 4; ++mt) {
        const int row = wm * 64 + mt * 16 + l15;
        af[mt] = *(const short8*)&sA[row * 64 + ((ks * 4 + quad) ^ (row & 7)) * 8];
      }
#pragma unroll
      for (int nt = 0; nt < 4; ++nt) {
        const int row = wn * 64 + nt * 16 + l15;
        bf[nt] = *(const short8*)&sB[row * 64 + ((ks * 4 + quad) ^ (row & 7)) * 8];
      }
#pragma unroll
      for (int mt = 0; mt < 4; ++mt)
#pragma unroll
        for (int nt = 0; nt < 4; ++nt)
          acc[mt][nt] = __builtin_amdgcn_mfma_f32_16x16x32_bf16(af[mt], bf[nt], acc[mt][nt], 0, 0, 0);
    }
  }
}

// epilogue: out[row,col] = acc + bias0[col] + bias1[col] (bias0==nullptr -> 0)
__device__ __forceinline__ void epi_store(
    floatx4 (&acc)[4][4], const float* __restrict__ bias0,
    const float* __restrict__ bias1, float* __restrict__ out,
    int N, int Mbase, int Nbase)
{
  const int tid = threadIdx.x, lane = tid & 63, w = tid >> 6;
  const int quad = lane >> 4, l15 = lane & 15;
  const int wm = w >> 1, wn = w & 1;
#pragma unroll
  for (int nt = 0; nt < 4; ++nt) {
    const int col = Nbase + wn * 64 + nt * 16 + l15;
    const float bc = bias0 ? (bias0[col] + bias1[col]) : 0.f;
#pragma unroll
    for (int mt = 0; mt < 4; ++mt) {
      const int rb = Mbase + wm * 64 + mt * 16 + quad * 4;
#pragma unroll
      for (int r = 0; r < 4; ++r)
        out[(size_t)(rb + r) * N + col] = acc[mt][nt][r] + bc;
    }
  }
}

// epilogue: atomicAdd per-row of sum_col Walpha[col]*tanh(acc + atth[b*512+col])
// (Mbase here is the GLOBAL score row base, i.e. includes row0.)
__device__ __forceinline__ void epi_score(
    floatx4 (&acc)[4][4], const float* __restrict__ atth,
    const float* __restrict__ Walpha, float* __restrict__ scores,
    int Mbase, int Nbase)
{
  const int tid = threadIdx.x, lane = tid & 63, w = tid >> 6;
  const int quad = lane >> 4, l15 = lane & 15;
  const int wm = w >> 1, wn = w & 1;
  const int b = (Mbase + wm * 64) >> 6;      // one batch per wave stripe
  float rs[4][4] = {};
#pragma unroll
  for (int nt = 0; nt < 4; ++nt) {
    const int col = Nbase + wn * 64 + nt * 16 + l15;
    const float wa = Walpha[col];
    const float ah = atth[(size_t)b * 512 + col];
#pragma unroll
    for (int mt = 0; mt < 4; ++mt)
#pragma unroll
      for (int r = 0; r < 4; ++r)
        rs[mt][r] += wa * fast_tanh(acc[mt][nt][r] + ah);
  }
#pragma unroll
  for (int mt = 0; mt < 4; ++mt)
#pragma unroll
    for (int r = 0; r < 4; ++r) {
      float v = rs[mt][r];
      v += __shfl_xor(v, 1); v += __shfl_xor(v, 2);
      v += __shfl_xor(v, 4); v += __shfl_xor(v, 8);
      if (l15 == 0)
        atomicAdd(&scores[Mbase + wm * 64 + mt * 16 + quad * 4 + r], v);
    }
}

// LSTM elementwise body; g1b != nullptr adds the second K-partial.
__device__ __forceinline__ void lstm_body(
    const float* __restrict__ gates, const float* __restrict__ g1b,
    const float* __restrict__ cprev, float* __restrict__ out, int st, int blk)
{
  const int idx = blk * 256 + (int)threadIdx.x;
  const int b = idx >> 8;
  const int r4 = (idx & 255) * 4;
  const float* g = gates + (size_t)b * 4096 + r4;
  float4 gi = *(const float4*)g;
  float4 gf = *(const float4*)(g + 1024);
  float4 gg = *(const float4*)(g + 2048);
  float4 go = *(const float4*)(g + 3072);
  if (g1b) {
    const float* h = g1b + (size_t)b * 4096 + r4;
    const float4 hi = *(const float4*)h;
    const float4 hf = *(const float4*)(h + 1024);
    const float4 hg = *(const float4*)(h + 2048);
    const float4 ho = *(const float4*)(h + 3072);
    gi.x += hi.x; gi.y += hi.y; gi.z += hi.z; gi.w += hi.w;
    gf.x += hf.x; gf.y += hf.y; gf.z += hf.z; gf.w += hf.w;
    gg.x += hg.x; gg.y += hg.y; gg.z += hg.z; gg.w += hg.w;
    go.x += ho.x; go.y += ho.y; go.z += ho.z; go.w += ho.w;
  }
  const float4 c = *(const float4*)(cprev + (size_t)b * 1024 + r4);
  float4 cn, hn;
  cn.x = fast_sigm(gf.x) * c.x + fast_sigm(gi.x) * fast_tanh(gg.x);  hn.x = fast_sigm(go.x) * fast_tanh(cn.x);
  cn.y = fast_sigm(gf.y) * c.y + fast_sigm(gi.y) * fast_tanh(gg.y);  hn.y = fast_sigm(go.y) * fast_tanh(cn.y);
  cn.z = fast_sigm(gf.z) * c.z + fast_sigm(gi.z) * fast_tanh(gg.z);  hn.z = fast_sigm(go.z) * fast_tanh(cn.z);
  cn.w = fast_sigm(gf.w) * c.w + fast_sigm(gi.w) * fast_tanh(gg.w);  hn.w = fast_sigm(go.w) * fast_tanh(cn.w);
  *(float4*)(out + (size_t)b * 2048 + st * 1024 + r4) = hn;
  *(float4*)(out + 2097152 + (size_t)st * 1048576 + (size_t)b * 1024 + r4) = hn;
  *(float4*)(out + 4194304 + (size_t)st * 1048576 + (size_t)b * 1024 + r4) = cn;
}

// ---------------------------------------------------------------------------
// Fallback-path kernels (kept verbatim in behavior)
template<int MODE>
__global__ __launch_bounds__(256, 3)
void gemm128(const u16* __restrict__ A, int sa, const u16* __restrict__ B, int sb,
             const float* __restrict__ bias0, const float* __restrict__ bias1,
             float* __restrict__ out, int N, int K,
             const float* __restrict__ atth, const float* __restrict__ Walpha,
             float* __restrict__ scores, int row0,
             const u16* A2, const u16* B2,
             const float* bias0b, const float* bias1b, float* out2)
{
  if (blockIdx.z) { A = A2; B = B2; bias0 = bias0b; bias1 = bias1b; out = out2; }
  __shared__ u16 sA[128 * 64];
  __shared__ u16 sB[128 * 64];
  const int Mbase = blockIdx.y * 128, Nbase = blockIdx.x * 128;
  floatx4 acc[4][4] = {};
  gemm_body(A, sa, B, sb, K, Mbase, Nbase, sA, sB, acc);
  if (MODE == 0) epi_store(acc, bias0, bias1, out, N, Mbase, Nbase);
  else           epi_score(acc, atth, Walpha, scores, row0 + Mbase, Nbase);
}

// masked softmax over S=64, one wave per batch (b_alpha constant cancels)
__global__ __launch_bounds__(256)
void softmax_k(const float* __restrict__ scores, const int* __restrict__ mask,
               float* __restrict__ wbuf)
{
  const int b = blockIdx.x * 4 + (threadIdx.x >> 6);
  const int s = threadIdx.x & 63;
  const float v = scores[b * 64 + s];
  float mx = v;
#pragma unroll
  for (int d = 32; d; d >>= 1) mx = fmaxf(mx, __shfl_xor(mx, d));
  const float e = __expf(v - mx) * (float)mask[b * 64 + s];
  float den = e;
#pragma unroll
  for (int d = 32; d; d >>= 1) den += __shfl_xor(den, d);
  wbuf[b * 64 + s] = e / den;
}

// att[b,:] = sum_s w[s]*clip[b,s,:] -> bf16 into A1 cols 1024..2047 (fallback)
template<int BF>
__global__ __launch_bounds__(128)
void ctx_att(const float* __restrict__ clipf, const u16* __restrict__ clipb,
             const float* __restrict__ wbuf, u16* __restrict__ A1)
{
  __shared__ float w[64];
  const int b = blockIdx.x, tid = threadIdx.x;
  if (tid < 64) w[tid] = wbuf[b * 64 + tid];
  __syncthreads();
  const int c8 = tid * 8;
  float a[8] = {};
  if (BF) {
    const u16* base = clipb + (size_t)b * 65536 + c8;
#pragma unroll 4
    for (int s = 0; s < 64; ++s) {
      const float wt = w[s];
      const short8 c = *(const short8*)(base + (size_t)s * 1024);
#pragma unroll
      for (int j = 0; j < 8; ++j) a[j] += wt * bf2f((u16)c[j]);
    }
  } else {
    const float* base = clipf + (size_t)b * 65536 + c8;
#pragma unroll 4
    for (int s = 0; s < 64; ++s) {
      const float wt = w[s];
      const float4 v0 = *(const float4*)(base + (size_t)s * 1024);
      const float4 v1 = *(const float4*)(base + (size_t)s * 1024 + 4);
      a[0] += wt * v0.x; a[1] += wt * v0.y; a[2] += wt * v0.z; a[3] += wt * v0.w;
      a[4] += wt * v1.x; a[5] += wt * v1.y; a[6] += wt * v1.z; a[7] += wt * v1.w;
    }
  }
  short8 p;
#pragma unroll
  for (int j = 0; j < 8; ++j) p[j] = (short)cvt_bf(a[j]);
  *(short8*)&A1[(size_t)b * 3072 + 1024 + c8] = p;
}

__global__ __launch_bounds__(256)
void lstm_ew(const float* __restrict__ gates, const float* __restrict__ cprev,
             float* __restrict__ out, int st)
{
  lstm_body(gates, nullptr, cprev, out, st, blockIdx.x);
}

// ---------------------------------------------------------------------------
// NEW fused-path kernels
// ---------------------------------------------------------------------------
// L2: clip fp32->bf16 (32768 blocks) + atth GEMM (32 blocks, dispatched FIRST
// so it overlaps the memory-bound conversion instead of running alone).
__global__ __launch_bounds__(256, 3)
void conv_atth(const float* __restrict__ clip, u16* __restrict__ clipb,
               const u16* __restrict__ A1, const u16* __restrict__ Wh,
               const float* __restrict__ b_h2a, const float* __restrict__ b_ctx,
               float* __restrict__ atth)
{
  __shared__ u16 sA[128 * 64];
  __shared__ u16 sB[128 * 64];
  const int bid = blockIdx.x;
  if (bid < 32) {          // atth = h1p @ W_h2a^T + b_h2a + b_ctx  [1024 x 512]
    const int Nbase = (bid & 3) * 128, Mbase = (bid >> 2) * 128;
    floatx4 acc[4][4] = {};
    gemm_body(A1 + 2048, 3072, Wh, 1024, 1024, Mbase, Nbase, sA, sB, acc);
    epi_store(acc, b_h2a, b_ctx, atth, 512, Mbase, Nbase);
    return;
  }
  const size_t e = (size_t)(bid - 32) * 2048 + threadIdx.x * 8;
  const float4 v0 = *(const float4*)(clip + e);
  const float4 v1 = *(const float4*)(clip + e + 4);
  short8 p;
  p[0] = (short)cvt_bf(v0.x); p[1] = (short)cvt_bf(v0.y);
  p[2] = (short)cvt_bf(v0.z); p[3] = (short)cvt_bf(v0.w);
  p[4] = (short)cvt_bf(v1.x); p[5] = (short)cvt_bf(v1.y);
  p[6] = (short)cvt_bf(v1.z); p[7] = (short)cvt_bf(v1.w);
  *(short8*)(clipb + e) = p;
}

// L3: gates0 GEMM (256 long K=3072 blocks, dispatched FIRST) + score GEMM
// (2048 blocks, K=1024, tanh/Walpha epilogue). gates0 is independent of the
// attention chain, so it rides along here instead of serializing at the end.
__global__ __launch_bounds__(256, 3)
void g0score(const u16* __restrict__ A0, const u16* __restrict__ W0,
             const float* __restrict__ bi0, const float* __restrict__ bh0,
             float* __restrict__ gates0,
             const u16* __restrict__ clipb, const u16* __restrict__ Wc,
             const float* __restrict__ atth, const float* __restrict__ Walpha,
             float* __restrict__ scores)
{
  __shared__ u16 sA[128 * 64];
  __shared__ u16 sB[128 * 64];
  floatx4 acc[4][4] = {};
  const int bid = blockIdx.x;
  if (bid < 256) {         // gates0 = A0 @ W0^T  [1024 x 4096], K=3072
    const int Nbase = (bid & 31) * 128, Mbase = (bid >> 5) * 128;
    gemm_body(A0, 3072, W0, 3072, 3072, Mbase, Nbase, sA, sB, acc);
    epi_store(acc, bi0, bh0, gates0, 4096, Mbase, Nbase);
  } else {                 // scores partial  [65536 x 512], K=1024
    const int t = bid - 256;
    const int Nbase = (t & 3) * 128, Mbase = (t >> 2) * 128;
    gemm_body(clipb, 1024, Wc, 1024, 1024, Mbase, Nbase, sA, sB, acc);
    epi_score(acc, atth, Walpha, scores, Mbase, Nbase);
  }
}

// L4: per-batch masked softmax (wave 0) fused with context reduction.
__global__ __launch_bounds__(128)
void sm_ctx(const float* __restrict__ scores, const int* __restrict__ cmask,
            const u16* __restrict__ clipb, u16* __restrict__ A1)
{
  __shared__ float w[64];
  const int b = blockIdx.x, tid = threadIdx.x;
  if (tid < 64) {          // exactly wave 0: no divergence inside the wave
    const float v = scores[b * 64 + tid];
    float mx = v;
#pragma unroll
    for (int d = 32; d; d >>= 1) mx = fmaxf(mx, __shfl_xor(mx, d));
    const float e = __expf(v - mx) * (float)cmask[b * 64 + tid];
    float den = e;
#pragma unroll
    for (int d = 32; d; d >>= 1) den += __shfl_xor(den, d);
    w[tid] = e / den;
  }
  __syncthreads();
  const int c8 = tid * 8;
  float a[8] = {};
  const u16* base = clipb + (size_t)b * 65536 + c8;
#pragma unroll 4
  for (int s = 0; s < 64; ++s) {
    const float wt = w[s];
    const short8 c = *(const short8*)(base + (size_t)s * 1024);
#pragma unroll
    for (int j = 0; j < 8; ++j) a[j] += wt * bf2f((u16)c[j]);
  }
  short8 p;
#pragma unroll
  for (int j = 0; j < 8; ++j) p[j] = (short)cvt_bf(a[j]);
  *(short8*)&A1[(size_t)b * 3072 + 1024 + c8] = p;
}

// L5: gates1 GEMM K-split x2 (512 blocks -> 2 blocks/CU instead of 1) fused
// with lstm_ew stream-0 (memory-bound blocks co-scheduled with MFMA blocks).
__global__ __launch_bounds__(256, 3)
void g1ew(const u16* __restrict__ A1, const u16* __restrict__ W1,
          const float* __restrict__ bi1, const float* __restrict__ bh1,
          float* __restrict__ g1a, float* __restrict__ g1b,
          const float* __restrict__ gates0, const float* __restrict__ c0p,
          float* __restrict__ out)
{
  __shared__ u16 sA[128 * 64];
  __shared__ u16 sB[128 * 64];
  const int bid = blockIdx.x;
  if (bid < 512) {
    floatx4 acc[4][4] = {};
    const int half = bid >> 8;              // 0: k in [0,1536), 1: [1536,3072)
    const int t = bid & 255;
    const int Nbase = (t & 31) * 128, Mbase = (t >> 5) * 128;
    const int k0 = half * 1536;
    gemm_body(A1 + k0, 3072, W1 + k0, 3072, 1536, Mbase, Nbase, sA, sB, acc);
    if (half == 0) epi_store(acc, bi1, bh1, g1a, 4096, Mbase, Nbase);
    else           epi_store(acc, nullptr, nullptr, g1b, 4096, Mbase, Nbase);
  } else {
    lstm_body(gates0, nullptr, c0p, out, 0, bid - 512);
  }
}

// L6: lstm_ew stream-1, summing the two K-partials.
__global__ __launch_bounds__(256)
void ew1sum(const float* __restrict__ g1a, const float* __restrict__ g1b,
            const float* __restrict__ c1p, float* __restrict__ out)
{
  lstm_body(g1a, g1b, c1p, out, 1, blockIdx.x);
}

// ---------------------------------------------------------------------------
extern "C" void kernel_launch(void* const* d_in, const int* in_sizes, int n_in,
                              void* d_out, int out_size, void* d_ws, size_t ws_size,
                              hipStream_t stream) {
  (void)in_sizes; (void)n_in; (void)out_size;
  const float* xt      = (const float*)d_in[0];
  const float* event   = (const float*)d_in[2];
  const float* clip    = (const float*)d_in[3];
  const int*   cmask   = (const int*)d_in[4];
  const float* state_h = (const float*)d_in[5];
  const float* state_c = (const float*)d_in[6];
  const float* W_ih0   = (const float*)d_in[7];
  const float* b_ih0   = (const float*)d_in[8];
  const float* W_hh0   = (const float*)d_in[9];
  const float* b_hh0   = (const float*)d_in[10];
  const float* W_ih1   = (const float*)d_in[11];
  const float* b_ih1   = (const float*)d_in[12];
  const float* W_hh1   = (const float*)d_in[13];
  const float* b_hh1   = (const float*)d_in[14];
  const float* W_ctx   = (const float*)d_in[15];
  const float* b_ctx   = (const float*)d_in[16];
  const float* W_h2a   = (const float*)d_in[17];
  const float* b_h2a   = (const float*)d_in[18];
  const float* W_alpha = (const float*)d_in[19];

  const float* h0p = state_h;
  const float* h1p = state_h + 1048576;
  const float* c0p = state_c;
  const float* c1p = state_c + 1048576;
  float* out = (float*)d_out;

  if (ws_size >= 251920384) {
    // ----- fused 6-launch path -----
    char* p = (char*)d_ws;
    float* gates0 = (float*)p; p += 16777216;   // [1024][4096]
    float* g1a    = (float*)p; p += 16777216;   // gates1 partial (k<1536, +bias)
    float* g1b    = (float*)p; p += 16777216;   // gates1 partial (k>=1536)
    u16* A0 = (u16*)p; p += 6291456;            // [1024][3072] = [xt|event|h0p]
    u16* A1 = (u16*)p; p += 6291456;            // [1024][3072] = [xt|att|h1p]
    u16* W0 = (u16*)p; p += 25165824;           // [4096][3072] = [W_ih0|W_hh0]
    u16* W1 = (u16*)p; p += 25165824;           // [4096][3072] = [W_ih1|W_hh1]
    u16* Wc = (u16*)p; p += 1048576;            // [512][1024]
    u16* Wh = (u16*)p; p += 1048576;            // [512][1024]
    u16* clipb = (u16*)p; p += 134217728;       // [65536][1024]
    float* atth   = (float*)p; p += 2097152;    // [1024][512]
    float* scores = (float*)p;                  // [1024][64]

    // L1: ALL fp32->bf16 conversions (incl. W1) + zero scores, one launch.
    ConvArgs ca{};
    {
      const float* srcs[12] = {W_ctx, W_h2a, W_ih0, W_hh0, W_ih1, W_hh1,
                               xt, event, h0p, xt, h1p, nullptr};
      u16* dsts[12] = {Wc, Wh, W0, W0 + 2048, W1, W1 + 2048,
                       A0, A0 + 1024, A0 + 2048, A1, A1 + 2048, (u16*)scores};
      const unsigned lws[12]  = {10, 10, 11, 10, 11, 10, 10, 10, 10, 10, 10, 17};
      const unsigned dstr[12] = {1024, 1024, 3072, 3072, 3072, 3072,
                                 3072, 3072, 3072, 3072, 3072, 0};
      const unsigned nblk[12] = {256, 256, 4096, 2048, 4096, 2048,
                                 512, 512, 512, 512, 512, 64};
      unsigned acc = 0;
      for (int i = 0; i < 12; ++i) {
        ca.src[i] = srcs[i]; ca.dst[i] = dsts[i];
        ca.lw[i] = lws[i]; ca.dstride[i] = dstr[i];
        ca.blk0[i] = acc; acc += nblk[i];
      }
      ca.blk0[12] = acc; ca.nseg = 12;
      convert_seg<<<acc, 256, 0, stream>>>(ca);     // 15424 blocks
    }

    // L2: clip conversion + atth GEMM (gemm blocks first -> hidden).
    conv_atth<<<32800, 256, 0, stream>>>(clip, clipb, A1, Wh, b_h2a, b_ctx, atth);

    // L3: gates0 GEMM + score GEMM in one launch (long blocks first).
    g0score<<<2304, 256, 0, stream>>>(A0, W0, b_ih0, b_hh0, gates0,
                                      clipb, Wc, atth, W_alpha, scores);

    // L4: softmax + context reduction -> bf16 att into A1.
    sm_ctx<<<1024, 128, 0, stream>>>(scores, cmask, clipb, A1);

    // L5: gates1 GEMM (K-split x2) + lstm_ew stream 0.
    g1ew<<<1536, 256, 0, stream>>>(A1, W1, b_ih1, b_hh1, g1a, g1b,
                                   gates0, c0p, out);

    // L6: lstm_ew stream 1 (sums the two partials).
    ew1sum<<<1024, 256, 0, stream>>>(g1a, g1b, c1p, out);
    return;
  }

  // ----- fallback: previous verified path -----
  int NC; bool grouped;
  if      (ws_size >= 207618048) { NC = 1; grouped = true;  }
  else if (ws_size >= 106954752) { NC = 4; grouped = true;  }
  else                           { NC = 8; grouped = false; }  // 81,788,928 B

  char* p = (char*)d_ws;
  float* gates0 = (float*)p; p += 16777216;
  float* gates1 = gates0;
  if (grouped) { gates1 = (float*)p; p += 16777216; }
  u16* A0 = (u16*)p; p += 6291456;      // [1024][3072] = [xt|event|h0p]
  u16* A1 = (u16*)p; p += 6291456;      // [1024][3072] = [xt|att|h1p]
  u16* W0 = (u16*)p; p += 25165824;     // [4096][3072] = [W_ih0|W_hh0]
  u16* Wc = (u16*)p; p += 1048576;      // [512][1024]
  u16* Wh = (u16*)p; p += 1048576;      // [512][1024]
  u16* clipb = (u16*)p;                 // chunk of bf16 clip
  u16* W1 = (u16*)p;                    // aliases clipb; converted AFTER ctx_att
  float* atth   = gates0;               // 1024*512
  float* wbuf   = gates0 + 524288;      // 1024*64
  float* scores = gates0 + 589824;      // 1024*64

  ConvArgs ca{};
  {
    const float* srcs[9] = {W_ctx, W_h2a, W_ih0, W_hh0, xt, event, h0p, xt, h1p};
    u16* dsts[9] = {Wc, Wh, W0, W0 + 2048, A0, A0 + 1024, A0 + 2048, A1, A1 + 2048};
    const unsigned lws[9]  = {10, 10, 11, 10, 10, 10, 10, 10, 10};
    const unsigned dstr[9] = {1024, 1024, 3072, 3072, 3072, 3072, 3072, 3072, 3072};
    const unsigned nblk[9] = {256, 256, 4096, 2048, 512, 512, 512, 512, 512};
    unsigned acc = 0;
    for (int i = 0; i < 9; ++i) {
      ca.src[i] = srcs[i]; ca.dst[i] = dsts[i];
      ca.lw[i] = lws[i]; ca.dstride[i] = dstr[i];
      ca.blk0[i] = acc; acc += nblk[i];
    }
    ca.blk0[9] = acc; ca.nseg = 9;
    convert_seg<<<acc, 256, 0, stream>>>(ca);   // 9216 blocks
  }

  zerof<<<256, 256, 0, stream>>>(scores);

  gemm128<0><<<dim3(4, 8, 1), 256, 0, stream>>>(
      A1 + 2048, 3072, Wh, 1024, b_h2a, b_ctx, atth, 512, 1024,
      nullptr, nullptr, nullptr, 0, nullptr, nullptr, nullptr, nullptr, nullptr);

  const int rows = 65536 / NC;
  for (int c = 0; c < NC; ++c) {
    conv_flat<<<rows * 1024 / 2048, 256, 0, stream>>>(clip + (size_t)c * rows * 1024, clipb);
    gemm128<1><<<dim3(4, rows / 128, 1), 256, 0, stream>>>(
        clipb, 1024, Wc, 1024, nullptr, nullptr, nullptr, 512, 1024,
        atth, W_alpha, scores, c * rows,
        nullptr, nullptr, nullptr, nullptr, nullptr);
  }

  softmax_k<<<256, 256, 0, stream>>>(scores, cmask, wbuf);

  if (NC == 1) ctx_att<1><<<1024, 128, 0, stream>>>(clip, clipb, wbuf, A1);
  else         ctx_att<0><<<1024, 128, 0, stream>>>(clip, clipb, wbuf, A1);

  ConvArgs cb{};
  {
    const float* srcs[2] = {W_ih1, W_hh1};
    u16* dsts[2] = {W1, W1 + 2048};
    const unsigned lws[2] = {11, 10};
    const unsigned nblk[2] = {4096, 2048};
    unsigned acc = 0;
    for (int i = 0; i < 2; ++i) {
      cb.src[i] = srcs[i]; cb.dst[i] = dsts[i];
      cb.lw[i] = lws[i]; cb.dstride[i] = 3072;
      cb.blk0[i] = acc; acc += nblk[i];
    }
    cb.blk0[2] = acc; cb.nseg = 2;
    convert_seg<<<acc, 256, 0, stream>>>(cb);   // 6144 blocks
  }

  if (grouped) {
    gemm128<0><<<dim3(32, 8, 2), 256, 0, stream>>>(
        A0, 3072, W0, 3072, b_ih0, b_hh0, gates0, 4096, 3072,
        nullptr, nullptr, nullptr, 0,
        A1, W1, b_ih1, b_hh1, gates1);
    lstm_ew<<<1024, 256, 0, stream>>>(gates0, c0p, out, 0);
    lstm_ew<<<1024, 256, 0, stream>>>(gates1, c1p, out, 1);
  } else {
    gemm128<0><<<dim3(32, 8, 1), 256, 0, stream>>>(
        A0, 3072, W0, 3072, b_ih0, b_hh0, gates0, 4096, 3072,
        nullptr, nullptr, nullptr, 0, nullptr, nullptr, nullptr, nullptr, nullptr);
    lstm_ew<<<1024, 256, 0, stream>>>(gates0, c0p, out, 0);
    gemm128<0><<<dim3(32, 8, 1), 256, 0, stream>>>(
        A1, 3072, W1, 3072, b_ih1, b_hh1, gates0, 4096, 3072,
        nullptr, nullptr, nullptr, 0, nullptr, nullptr, nullptr, nullptr, nullptr);
    lstm_ew<<<1024, 256, 0, stream>>>(gates0, c1p, out, 1);
  }
}